// Round 1
// baseline (1633.588 us; speedup 1.0000x reference)
//
#include <hip/hip_runtime.h>

#define NB 8
#define NS 2048
#define ND 256
#define NH 4
#define NHD 64
#define ND2 512
#define NM (NB * NS)

// ---------------------------------------------------------------------------
// Generic fp32 tiled GEMM: C[M,N] = epilogue(A @ W + bias)
// A row-major, split column-wise: cols [0,K0) from A0 (ld=K0), cols [K0,K)
// from A1 (ld=K-K0). BK=16 divides 256, so a K-tile never straddles the seam.
// epilogue: use_bn ? relu(batchnorm(x)) : x
// BM=BN=128, BK=16, 256 threads, 8x8 micro-tile per thread.
// ---------------------------------------------------------------------------
__global__ __launch_bounds__(256) void gemm_kernel(
    const float* __restrict__ A0, const float* __restrict__ A1, int K0,
    const float* __restrict__ W, const float* __restrict__ bias,
    const float* __restrict__ bng, const float* __restrict__ bnb,
    const float* __restrict__ bnm, const float* __restrict__ bnv,
    int use_bn, float* C, int M, int N, int K)
{
    __shared__ float As[16][128];
    __shared__ float Ws[16][132];

    const int t  = threadIdx.x;
    const int tx = t & 15;
    const int ty = t >> 4;
    const int bm = blockIdx.y << 7;
    const int bn = blockIdx.x << 7;

    const int a_row = t >> 2;          // 0..63
    const int a_col = (t & 3) << 2;    // 0,4,8,12
    const int w_row = t >> 5;          // 0..7
    const int w_col = (t & 31) << 2;   // 0..124

    float acc[8][8];
#pragma unroll
    for (int i = 0; i < 8; i++)
#pragma unroll
        for (int j = 0; j < 8; j++) acc[i][j] = 0.0f;

    for (int kt = 0; kt < K; kt += 16) {
        const bool first  = (kt < K0);
        const float* Asrc = first ? A0 : A1;
        const int lda     = first ? K0 : (K - K0);
        const int kb      = first ? kt : (kt - K0);
        __syncthreads();
#pragma unroll
        for (int i = 0; i < 2; i++) {
            const int r = a_row + (i << 6);
            const float4 av =
                *(const float4*)(Asrc + (size_t)(bm + r) * lda + kb + a_col);
            As[a_col + 0][r] = av.x;
            As[a_col + 1][r] = av.y;
            As[a_col + 2][r] = av.z;
            As[a_col + 3][r] = av.w;
        }
#pragma unroll
        for (int i = 0; i < 2; i++) {
            const int r = w_row + (i << 3);
            *(float4*)(&Ws[r][w_col]) =
                *(const float4*)(W + (size_t)(kt + r) * N + bn + w_col);
        }
        __syncthreads();
#pragma unroll
        for (int kk = 0; kk < 16; kk++) {
            float a[8], w[8];
#pragma unroll
            for (int i = 0; i < 8; i++) a[i] = As[kk][ty * 8 + i];
#pragma unroll
            for (int j = 0; j < 8; j++) w[j] = Ws[kk][tx * 8 + j];
#pragma unroll
            for (int i = 0; i < 8; i++)
#pragma unroll
                for (int j = 0; j < 8; j++) acc[i][j] += a[i] * w[j];
        }
    }

#pragma unroll
    for (int i = 0; i < 8; i++) {
        const int row = bm + ty * 8 + i;
#pragma unroll
        for (int j = 0; j < 8; j++) {
            const int col = bn + tx * 8 + j;
            float v = acc[i][j] + bias[col];
            if (use_bn) {
                v = (v - bnm[col]) * rsqrtf(bnv[col] + 1e-5f) * bng[col] + bnb[col];
                v = fmaxf(v, 0.0f);
            }
            C[(size_t)row * N + col] = v;
        }
    }
}

// ---------------------------------------------------------------------------
// Flash-style cross-attention, fp32. Grid (S/64, H, B), 256 threads.
// Q tile 64x64 resident in LDS; stream K/V 64-row tiles; online softmax.
// Writes ctx back in [B,S,D] layout (head h occupies cols h*64..h*64+63).
// ctx may alias q: a block only reads its own Q rows/head-stripe (into LDS at
// start) and writes exactly those addresses at the end; other blocks never
// read them.
// ---------------------------------------------------------------------------
__global__ __launch_bounds__(256) void attn_kernel(
    const float* __restrict__ q, const float* __restrict__ k,
    const float* __restrict__ v, const int* __restrict__ mask,
    float* ctx)
{
    __shared__ float Qs[64][68];
    __shared__ float Ks[64][68];
    __shared__ float Vs[64][68];
    __shared__ float Ss[64][68];
    __shared__ float mrow[64], lrow[64], arow[64];
    __shared__ float pmax[4][64], psum[4][64];

    const int t    = threadIdx.x;
    const int tx   = t & 15;   // k / d group
    const int ty   = t >> 4;   // q group
    const int qb   = blockIdx.x;
    const int h    = blockIdx.y;
    const int b    = blockIdx.z;
    const int r64  = t & 63;
    const int part = t >> 6;

    // load Q tile (64 rows x 64 cols)
#pragma unroll
    for (int it = 0; it < 4; it++) {
        const int idx = t + it * 256;
        const int r = idx >> 4;
        const int c = (idx & 15) << 2;
        *(float4*)(&Qs[r][c]) =
            *(const float4*)(q + (size_t)(b * NS + qb * 64 + r) * ND + h * NHD + c);
    }
    if (t < 64) { mrow[t] = -1e30f; lrow[t] = 0.0f; }

    float O[4][4];
#pragma unroll
    for (int i = 0; i < 4; i++)
#pragma unroll
        for (int j = 0; j < 4; j++) O[i][j] = 0.0f;

    __syncthreads();

    for (int kt = 0; kt < NS / 64; kt++) {
        // load K,V tiles
#pragma unroll
        for (int it = 0; it < 4; it++) {
            const int idx = t + it * 256;
            const int r = idx >> 4;
            const int c = (idx & 15) << 2;
            const size_t g = (size_t)(b * NS + kt * 64 + r) * ND + h * NHD + c;
            *(float4*)(&Ks[r][c]) = *(const float4*)(k + g);
            *(float4*)(&Vs[r][c]) = *(const float4*)(v + g);
        }
        __syncthreads();

        // scores: 4q x 4k per thread, dot over d=64
        float s[4][4];
#pragma unroll
        for (int i = 0; i < 4; i++)
#pragma unroll
            for (int j = 0; j < 4; j++) s[i][j] = 0.0f;
#pragma unroll
        for (int d = 0; d < NHD; d += 4) {
            float4 qv[4], kv[4];
#pragma unroll
            for (int i = 0; i < 4; i++) qv[i] = *(const float4*)(&Qs[ty * 4 + i][d]);
#pragma unroll
            for (int j = 0; j < 4; j++) kv[j] = *(const float4*)(&Ks[tx * 4 + j][d]);
#pragma unroll
            for (int i = 0; i < 4; i++)
#pragma unroll
                for (int j = 0; j < 4; j++)
                    s[i][j] += qv[i].x * kv[j].x + qv[i].y * kv[j].y
                             + qv[i].z * kv[j].z + qv[i].w * kv[j].w;
        }
        int mv[4];
#pragma unroll
        for (int j = 0; j < 4; j++) mv[j] = mask[b * NS + kt * 64 + tx * 4 + j];
#pragma unroll
        for (int i = 0; i < 4; i++)
#pragma unroll
            for (int j = 0; j < 4; j++) {
                float val = s[i][j] * 0.125f;  // 1/sqrt(64)
                if (mv[j] == 0) val = -1e9f;
                Ss[ty * 4 + i][tx * 4 + j] = val;
            }
        __syncthreads();

        // online softmax: partial row max (4 threads per row, 16 cols each)
        float mx = -1e30f;
#pragma unroll
        for (int c = 0; c < 16; c++) mx = fmaxf(mx, Ss[r64][part * 16 + c]);
        pmax[part][r64] = mx;
        __syncthreads();
        if (t < 64) {
            float mnew = fmaxf(fmaxf(pmax[0][t], pmax[1][t]),
                               fmaxf(pmax[2][t], pmax[3][t]));
            mnew = fmaxf(mnew, mrow[t]);
            arow[t] = __expf(mrow[t] - mnew);
            mrow[t] = mnew;
        }
        __syncthreads();
        const float mnew = mrow[r64];
        float sum = 0.0f;
#pragma unroll
        for (int c = 0; c < 16; c++) {
            const float p = __expf(Ss[r64][part * 16 + c] - mnew);
            Ss[r64][part * 16 + c] = p;
            sum += p;
        }
        psum[part][r64] = sum;
        __syncthreads();
        if (t < 64)
            lrow[t] = lrow[t] * arow[t]
                    + psum[0][t] + psum[1][t] + psum[2][t] + psum[3][t];

        // rescale accumulators + P@V
        float al[4];
#pragma unroll
        for (int i = 0; i < 4; i++) al[i] = arow[ty * 4 + i];
#pragma unroll
        for (int i = 0; i < 4; i++)
#pragma unroll
            for (int j = 0; j < 4; j++) O[i][j] *= al[i];
#pragma unroll 4
        for (int kk = 0; kk < 64; kk++) {
            const float4 vv = *(const float4*)(&Vs[kk][tx * 4]);
#pragma unroll
            for (int i = 0; i < 4; i++) {
                const float p = Ss[ty * 4 + i][kk];
                O[i][0] += p * vv.x;
                O[i][1] += p * vv.y;
                O[i][2] += p * vv.z;
                O[i][3] += p * vv.w;
            }
        }
        __syncthreads();
    }

    float linv[4];
#pragma unroll
    for (int i = 0; i < 4; i++) linv[i] = 1.0f / lrow[ty * 4 + i];
#pragma unroll
    for (int i = 0; i < 4; i++) {
        float4 o;
        o.x = O[i][0] * linv[i];
        o.y = O[i][1] * linv[i];
        o.z = O[i][2] * linv[i];
        o.w = O[i][3] * linv[i];
        *(float4*)(ctx + (size_t)(b * NS + qb * 64 + ty * 4 + i) * ND + h * NHD + tx * 4) = o;
    }
}

extern "C" void kernel_launch(void* const* d_in, const int* in_sizes, int n_in,
                              void* d_out, int out_size, void* d_ws, size_t ws_size,
                              hipStream_t stream)
{
    (void)in_sizes; (void)n_in; (void)out_size; (void)ws_size;
    const float* desc = (const float*)d_in[0];
    const float* srcp = (const float*)d_in[1];
    const int*   mask = (const int*)d_in[2];
    const float* q_w  = (const float*)d_in[3];
    const float* q_b  = (const float*)d_in[4];
    const float* k_w  = (const float*)d_in[5];
    const float* k_b  = (const float*)d_in[6];
    const float* v_w  = (const float*)d_in[7];
    const float* v_b  = (const float*)d_in[8];
    const float* o_w  = (const float*)d_in[9];
    const float* o_b  = (const float*)d_in[10];
    const float* m0_w = (const float*)d_in[11];
    const float* m0_b = (const float*)d_in[12];
    const float* bng  = (const float*)d_in[13];
    const float* bnb  = (const float*)d_in[14];
    const float* bnm  = (const float*)d_in[15];
    const float* bnv  = (const float*)d_in[16];
    const float* m1_w = (const float*)d_in[17];
    const float* m1_b = (const float*)d_in[18];
    float* out = (float*)d_out;

    // workspace layout (fp32), 4*NM*ND floats = 67.1 MB total:
    //   [0,SZ)    qbuf  -> reused as ctx by attn_kernel (safe, see kernel)
    //   [SZ,2SZ)  kbuf  -> reused (with vbuf) as hbuf [NM,512] after attention
    //   [2SZ,3SZ) vbuf
    //   [3SZ,4SZ) abuf  (attn out_proj result)
    const size_t SZ = (size_t)NM * ND;
    float* ws   = (float*)d_ws;
    float* qbuf = ws;
    float* kbuf = ws + SZ;
    float* vbuf = ws + 2 * SZ;
    float* abuf = ws + 3 * SZ;
    float* hbuf = kbuf;  // spans kbuf..vbuf end: NM*512 floats

    const dim3 blk(256);
    const dim3 gq(ND / 128, NM / 128);   // N=256 GEMMs
    const dim3 gh(ND2 / 128, NM / 128);  // N=512 GEMM

    // Q, K, V projections
    gemm_kernel<<<gq, blk, 0, stream>>>(desc, desc, ND, q_w, q_b,
                                        bng, bnb, bnm, bnv, 0, qbuf, NM, ND, ND);
    gemm_kernel<<<gq, blk, 0, stream>>>(srcp, srcp, ND, k_w, k_b,
                                        bng, bnb, bnm, bnv, 0, kbuf, NM, ND, ND);
    gemm_kernel<<<gq, blk, 0, stream>>>(srcp, srcp, ND, v_w, v_b,
                                        bng, bnb, bnm, bnv, 0, vbuf, NM, ND, ND);
    // attention (ctx overwrites qbuf)
    attn_kernel<<<dim3(NS / 64, NH, NB), blk, 0, stream>>>(qbuf, kbuf, vbuf, mask, qbuf);
    // out_proj
    gemm_kernel<<<gq, blk, 0, stream>>>(qbuf, qbuf, ND, o_w, o_b,
                                        bng, bnb, bnm, bnv, 0, abuf, NM, ND, ND);
    // MLP0: concat(desc, attn) @ m0_w + bias -> BN -> ReLU
    gemm_kernel<<<gh, blk, 0, stream>>>(desc, abuf, ND, m0_w, m0_b,
                                        bng, bnb, bnm, bnv, 1, hbuf, NM, ND2, ND2);
    // MLP1 -> output
    gemm_kernel<<<gq, blk, 0, stream>>>(hbuf, hbuf, ND2, m1_w, m1_b,
                                        bng, bnb, bnm, bnv, 0, out, NM, ND, ND2);
}

// Round 3
// 569.158 us; speedup vs baseline: 2.8702x; 2.8702x over previous
//
#include <hip/hip_runtime.h>

#define NB 8
#define NS 2048
#define ND 256
#define NH 4
#define NHD 64
#define ND2 512
#define NM (NB * NS)
#define PITCH 72  // padded LDS row pitch in bf16 elems

typedef __attribute__((ext_vector_type(8))) short     bf16x8;
typedef __attribute__((ext_vector_type(8))) unsigned short u16x8;
typedef __attribute__((ext_vector_type(4))) float     f32x4;
typedef unsigned short ushort_t;
typedef unsigned int   uint_t;

#define MFMA16(a, b, c) __builtin_amdgcn_mfma_f32_16x16x32_bf16(a, b, c, 0, 0, 0)

static __device__ inline ushort_t f2bf(float f) {
    union { float f; uint_t u; } x; x.f = f;
    uint_t r = (x.u + 0x7FFFu + ((x.u >> 16) & 1u)) >> 16;
    return (ushort_t)r;
}

// ---------------------------------------------------------------------------
// fp32 tiled GEMM: C = epilogue(A @ W + bias)
// A split column-wise: cols [0,K0) from A0, cols [K0,K) from A1. BK=16.
// mode 0: fp32 out. mode 1: fp32 BN+ReLU. mode 2: bf16 head-major
// [b][h][s][64]. mode 3: bf16 head-transposed [b][h][dv][s].
// ---------------------------------------------------------------------------
__global__ __launch_bounds__(256) void gemm_kernel(
    const float* __restrict__ A0, const float* __restrict__ A1, int K0,
    const float* __restrict__ W, const float* __restrict__ bias,
    const float* __restrict__ bng, const float* __restrict__ bnb,
    const float* __restrict__ bnm, const float* __restrict__ bnv,
    int mode, float* C, ushort_t* Cb, int M, int N, int K)
{
    __shared__ float As[16][128];
    __shared__ float Ws[16][132];

    const int t  = threadIdx.x;
    const int tx = t & 15;
    const int ty = t >> 4;
    const int bm = blockIdx.y << 7;
    const int bn = blockIdx.x << 7;

    const int a_row = t >> 2;
    const int a_col = (t & 3) << 2;
    const int w_row = t >> 5;
    const int w_col = (t & 31) << 2;

    float acc[8][8];
#pragma unroll
    for (int i = 0; i < 8; i++)
#pragma unroll
        for (int j = 0; j < 8; j++) acc[i][j] = 0.0f;

    for (int kt = 0; kt < K; kt += 16) {
        const bool first  = (kt < K0);
        const float* Asrc = first ? A0 : A1;
        const int lda     = first ? K0 : (K - K0);
        const int kb      = first ? kt : (kt - K0);
        __syncthreads();
#pragma unroll
        for (int i = 0; i < 2; i++) {
            const int r = a_row + (i << 6);
            const float4 av =
                *(const float4*)(Asrc + (size_t)(bm + r) * lda + kb + a_col);
            As[a_col + 0][r] = av.x;
            As[a_col + 1][r] = av.y;
            As[a_col + 2][r] = av.z;
            As[a_col + 3][r] = av.w;
        }
#pragma unroll
        for (int i = 0; i < 2; i++) {
            const int r = w_row + (i << 3);
            *(float4*)(&Ws[r][w_col]) =
                *(const float4*)(W + (size_t)(kt + r) * N + bn + w_col);
        }
        __syncthreads();
#pragma unroll
        for (int kk = 0; kk < 16; kk++) {
            float a[8], w[8];
#pragma unroll
            for (int i = 0; i < 8; i++) a[i] = As[kk][ty * 8 + i];
#pragma unroll
            for (int j = 0; j < 8; j++) w[j] = Ws[kk][tx * 8 + j];
#pragma unroll
            for (int i = 0; i < 8; i++)
#pragma unroll
                for (int j = 0; j < 8; j++) acc[i][j] += a[i] * w[j];
        }
    }

    const int c0 = bn + tx * 8;
    if (mode <= 1) {
#pragma unroll
        for (int i = 0; i < 8; i++) {
            const int row = bm + ty * 8 + i;
#pragma unroll
            for (int j = 0; j < 8; j++) {
                const int col = c0 + j;
                float v = acc[i][j] + bias[col];
                if (mode == 1) {
                    v = (v - bnm[col]) * rsqrtf(bnv[col] + 1e-5f) * bng[col] + bnb[col];
                    v = fmaxf(v, 0.0f);
                }
                C[(size_t)row * N + col] = v;
            }
        }
    } else if (mode == 2) {
        // bf16 head-major: [b][h][s][64]
        const int h = c0 >> 6;
        const int dv0 = c0 & 63;
#pragma unroll
        for (int i = 0; i < 8; i++) {
            const int row = bm + ty * 8 + i;
            const int b = row >> 11;
            const int s = row & 2047;
            u16x8 pk;
#pragma unroll
            for (int j = 0; j < 8; j++) pk[j] = f2bf(acc[i][j] + bias[c0 + j]);
            *(u16x8*)(Cb + ((size_t)(b * NH + h) * NS + s) * NHD + dv0) = pk;
        }
    } else {
        // bf16 head-transposed: [b][h][dv][s]
        const int row0 = bm + ty * 8;
        const int b = row0 >> 11;
        const int s0 = row0 & 2047;
#pragma unroll
        for (int j = 0; j < 8; j++) {
            const int col = c0 + j;
            const int h = col >> 6;
            const int dv = col & 63;
            u16x8 pk;
#pragma unroll
            for (int i = 0; i < 8; i++) pk[i] = f2bf(acc[i][j] + bias[col]);
            *(u16x8*)(Cb + ((size_t)(b * NH + h) * NHD + dv) * NS + s0) = pk;
        }
    }
}

// ---------------------------------------------------------------------------
// MFMA flash cross-attention (bf16 in, fp32 out).
// Grid (S/128, H, B), 256 threads = 4 waves. Wave handles 32 q rows (2 tiles
// of 16). Per 64-key chunk, per q-tile: S^T = K·Q^T (C-layout col = q ->
// cheap column softmax), P packed bf16 -> per-wave LDS, immediately consumed
// by ctx^T += V^T·P (P consumption is INSIDE the qt loop: Pl[w] holds only
// one q-tile's P at a time — round-2 bug was qt=1 overwriting qt=0's P
// before its PV reads).
// Verified layouts: A[m=lane&15][k=(lane>>4)*8+j]; B[n=lane&15][k=...];
// C/D row=(lane>>4)*4+reg, col=lane&15.
// ---------------------------------------------------------------------------
__global__ __launch_bounds__(256) void attn_mfma(
    const ushort_t* __restrict__ qbf, const ushort_t* __restrict__ kbf,
    const ushort_t* __restrict__ vtbf, const int* __restrict__ mask,
    float* __restrict__ ctx)
{
    __shared__ ushort_t Kl[64 * PITCH];
    __shared__ ushort_t Vl[64 * PITCH];
    __shared__ ushort_t Pl[4][16 * PITCH];

    const int t  = threadIdx.x;
    const int w  = t >> 6;
    const int l  = t & 63;
    const int lq = l & 15;   // q column within tile / A-row within tile
    const int lg = l >> 4;   // lane group
    const int qb = blockIdx.x;
    const int h  = blockIdx.y;
    const int b  = blockIdx.z;
    const int bh = b * NH + h;

    const ushort_t* qh = qbf + (size_t)bh * NS * NHD;
    const ushort_t* kh = kbf + (size_t)bh * NS * NHD;
    const ushort_t* vh = vtbf + (size_t)bh * NHD * NS;
    const int* mrow = mask + b * NS;
    const int qrow0 = qb * 128 + w * 32;

    // Q fragments (B-operand): lane holds Q[q=lq][d = dh*32 + lg*8 + j]
    bf16x8 qf[2][2];
#pragma unroll
    for (int qt = 0; qt < 2; qt++)
#pragma unroll
        for (int dh = 0; dh < 2; dh++)
            qf[qt][dh] = *(const bf16x8*)(qh + (size_t)(qrow0 + qt * 16 + lq) * NHD
                                          + dh * 32 + lg * 8);

    f32x4 o[2][4];
#pragma unroll
    for (int qt = 0; qt < 2; qt++)
#pragma unroll
        for (int dt = 0; dt < 4; dt++) o[qt][dt] = (f32x4){0.f, 0.f, 0.f, 0.f};
    float m_run[2] = {-1e30f, -1e30f};
    float l_run[2] = {0.0f, 0.0f};

    for (int key0 = 0; key0 < NS; key0 += 64) {
        __syncthreads();  // previous chunk's K/V frag reads done before overwrite
        // stage K [64 keys][64 d] and V^T [64 dv][64 keys] into padded LDS
#pragma unroll
        for (int i = 0; i < 2; i++) {
            const int r  = (t >> 3) + i * 32;
            const int c8 = (t & 7) * 8;
            *(bf16x8*)&Kl[r * PITCH + c8] =
                *(const bf16x8*)(kh + (size_t)(key0 + r) * NHD + c8);
            *(bf16x8*)&Vl[r * PITCH + c8] =
                *(const bf16x8*)(vh + (size_t)r * NS + key0 + c8);
        }
        __syncthreads();

        // mask for this lane's key rows: key = key0 + kt*16 + lg*4 + r
        int4 mv[4];
#pragma unroll
        for (int kt = 0; kt < 4; kt++)
            mv[kt] = *(const int4*)(mrow + key0 + kt * 16 + lg * 4);

#pragma unroll
        for (int qt = 0; qt < 2; qt++) {
            // S^T[key][q] = sum_d K[key][d] Q[q][d]
            f32x4 st[4];
#pragma unroll
            for (int kt = 0; kt < 4; kt++) {
                bf16x8 ka0 = *(const bf16x8*)&Kl[(kt * 16 + lq) * PITCH + lg * 8];
                bf16x8 ka1 = *(const bf16x8*)&Kl[(kt * 16 + lq) * PITCH + 32 + lg * 8];
                f32x4 a = (f32x4){0.f, 0.f, 0.f, 0.f};
                a = MFMA16(ka0, qf[qt][0], a);
                a = MFMA16(ka1, qf[qt][1], a);
                st[kt] = a;
            }
            // scale + mask + chunk column-max
            float cm = -1e30f;
#pragma unroll
            for (int kt = 0; kt < 4; kt++)
#pragma unroll
                for (int r = 0; r < 4; r++) {
                    float v = st[kt][r] * 0.125f;
                    const int mk = (&mv[kt].x)[r];
                    v = (mk == 0) ? -1e9f : v;
                    st[kt][r] = v;
                    cm = fmaxf(cm, v);
                }
            cm = fmaxf(cm, __shfl_xor(cm, 16));
            cm = fmaxf(cm, __shfl_xor(cm, 32));
            const float mn = fmaxf(m_run[qt], cm);
            const float al = __expf(m_run[qt] - mn);
            m_run[qt] = mn;
            // p = exp(s - mn); column sum; pack bf16 into per-wave LDS
            float ls = 0.0f;
#pragma unroll
            for (int kt = 0; kt < 4; kt++) {
                ushort_t pb[4];
#pragma unroll
                for (int r = 0; r < 4; r++) {
                    const float p = __expf(st[kt][r] - mn);
                    ls += p;
                    pb[r] = f2bf(p);
                }
                uint2 pv;
                pv.x = (uint_t)pb[0] | ((uint_t)pb[1] << 16);
                pv.y = (uint_t)pb[2] | ((uint_t)pb[3] << 16);
                *(uint2*)&Pl[w][lq * PITCH + kt * 16 + lg * 4] = pv;
            }
            ls += __shfl_xor(ls, 16);
            ls += __shfl_xor(ls, 32);
            l_run[qt] = l_run[qt] * al + ls;
            // rescale ctx^T accumulators (col = q = lq -> per-lane al)
#pragma unroll
            for (int dt = 0; dt < 4; dt++)
#pragma unroll
                for (int r = 0; r < 4; r++) o[qt][dt][r] *= al;

            // consume THIS q-tile's P before the next overwrites Pl[w].
            // P B-fragments: lane holds P[q=lq][key = kh2*32 + lg*8 + j]
            bf16x8 pf[2];
#pragma unroll
            for (int kh2 = 0; kh2 < 2; kh2++)
                pf[kh2] = *(const bf16x8*)&Pl[w][lq * PITCH + kh2 * 32 + lg * 8];

            // ctx^T[dv][q] += sum_key V^T[dv][key] P[q][key]
#pragma unroll
            for (int dt = 0; dt < 4; dt++)
#pragma unroll
                for (int kh2 = 0; kh2 < 2; kh2++) {
                    bf16x8 vf = *(const bf16x8*)&Vl[(dt * 16 + lq) * PITCH
                                                    + kh2 * 32 + lg * 8];
                    o[qt][dt] = MFMA16(vf, pf[kh2], o[qt][dt]);
                }
        }
    }

    // epilogue: divide by l, write ctx[token][256] fp32
#pragma unroll
    for (int qt = 0; qt < 2; qt++) {
        const float li = 1.0f / l_run[qt];
        const int tok = b * NS + qrow0 + qt * 16 + lq;
#pragma unroll
        for (int dt = 0; dt < 4; dt++) {
            f32x4 r = o[qt][dt];
            r[0] *= li; r[1] *= li; r[2] *= li; r[3] *= li;
            *(f32x4*)(ctx + (size_t)tok * ND + h * NHD + dt * 16 + lg * 4) = r;
        }
    }
}

extern "C" void kernel_launch(void* const* d_in, const int* in_sizes, int n_in,
                              void* d_out, int out_size, void* d_ws, size_t ws_size,
                              hipStream_t stream)
{
    (void)in_sizes; (void)n_in; (void)out_size; (void)ws_size;
    const float* desc = (const float*)d_in[0];
    const float* srcp = (const float*)d_in[1];
    const int*   mask = (const int*)d_in[2];
    const float* q_w  = (const float*)d_in[3];
    const float* q_b  = (const float*)d_in[4];
    const float* k_w  = (const float*)d_in[5];
    const float* k_b  = (const float*)d_in[6];
    const float* v_w  = (const float*)d_in[7];
    const float* v_b  = (const float*)d_in[8];
    const float* o_w  = (const float*)d_in[9];
    const float* o_b  = (const float*)d_in[10];
    const float* m0_w = (const float*)d_in[11];
    const float* m0_b = (const float*)d_in[12];
    const float* bng  = (const float*)d_in[13];
    const float* bnb  = (const float*)d_in[14];
    const float* bnm  = (const float*)d_in[15];
    const float* bnv  = (const float*)d_in[16];
    const float* m1_w = (const float*)d_in[17];
    const float* m1_b = (const float*)d_in[18];
    float* out = (float*)d_out;

    // workspace layout (<= 58.7 MB of the >=67.1 MB ws):
    //   [0, 8.4M)    qbf  bf16 [b][h][s][64]
    //   [8.4, 16.8M) kbf  bf16 [b][h][s][64]
    //   [16.8,25.2M) vtbf bf16 [b][h][dv][s]
    //   [25.2,41.9M) ctx  fp32 [NM][256]
    //   [41.9,58.7M) abuf fp32 [NM][256]
    //   hbuf fp32 [NM][512] at [0,33.6M) — overlaps qkv+ctx head, both dead
    //   by the time MLP0 runs (stream-ordered).
    const size_t HSZ = (size_t)NB * NH * NS * NHD;  // 4,194,304 elems
    ushort_t* qbf  = (ushort_t*)d_ws;
    ushort_t* kbf  = qbf + HSZ;
    ushort_t* vtbf = kbf + HSZ;
    float* ctx  = (float*)((char*)d_ws + 3 * HSZ * sizeof(ushort_t));
    float* abuf = ctx + (size_t)NM * ND;
    float* hbuf = (float*)d_ws;

    const dim3 blk(256);
    const dim3 gq(ND / 128, NM / 128);
    const dim3 gh(ND2 / 128, NM / 128);

    // QKV projections -> bf16 head layouts
    gemm_kernel<<<gq, blk, 0, stream>>>(desc, desc, ND, q_w, q_b,
                                        bng, bnb, bnm, bnv, 2, nullptr, qbf, NM, ND, ND);
    gemm_kernel<<<gq, blk, 0, stream>>>(srcp, srcp, ND, k_w, k_b,
                                        bng, bnb, bnm, bnv, 2, nullptr, kbf, NM, ND, ND);
    gemm_kernel<<<gq, blk, 0, stream>>>(srcp, srcp, ND, v_w, v_b,
                                        bng, bnb, bnm, bnv, 3, nullptr, vtbf, NM, ND, ND);
    // MFMA flash attention -> ctx fp32
    attn_mfma<<<dim3(NS / 128, NH, NB), blk, 0, stream>>>(qbf, kbf, vtbf, mask, ctx);
    // out_proj
    gemm_kernel<<<gq, blk, 0, stream>>>(ctx, ctx, ND, o_w, o_b,
                                        bng, bnb, bnm, bnv, 0, abuf, nullptr, NM, ND, ND);
    // MLP0: concat(desc, attn) @ m0_w -> BN -> ReLU
    gemm_kernel<<<gh, blk, 0, stream>>>(desc, abuf, ND, m0_w, m0_b,
                                        bng, bnb, bnm, bnv, 1, hbuf, nullptr, NM, ND2, ND2);
    // MLP1 -> out
    gemm_kernel<<<gq, blk, 0, stream>>>(hbuf, hbuf, ND2, m1_w, m1_b,
                                        bng, bnb, bnm, bnv, 0, out, nullptr, NM, ND, ND2);
}

// Round 4
// 304.497 us; speedup vs baseline: 5.3649x; 1.8692x over previous
//
#include <hip/hip_runtime.h>

#define NB 8
#define NS 2048
#define ND 256
#define NH 4
#define NHD 64
#define ND2 512
#define NM (NB * NS)
#define PITCH 72  // padded LDS row pitch in bf16 elems

typedef __attribute__((ext_vector_type(8))) short          bf16x8;
typedef __attribute__((ext_vector_type(8))) unsigned short u16x8;
typedef __attribute__((ext_vector_type(4))) float          f32x4;
typedef unsigned short ushort_t;
typedef unsigned int   uint_t;

#define MFMA16(a, b, c) __builtin_amdgcn_mfma_f32_16x16x32_bf16(a, b, c, 0, 0, 0)

static __device__ inline ushort_t f2bf(float f) {
    union { float f; uint_t u; } x; x.f = f;
    uint_t r = (x.u + 0x7FFFu + ((x.u >> 16) & 1u)) >> 16;
    return (ushort_t)r;
}

// ---------------------------------------------------------------------------
// fp32 -> bf16 convert for desc / source (grid.y selects buffer)
// ---------------------------------------------------------------------------
__global__ __launch_bounds__(256) void convert_acts(
    const float* __restrict__ d, const float* __restrict__ s,
    ushort_t* __restrict__ db, ushort_t* __restrict__ sb)
{
    const float* src = blockIdx.y ? s : d;
    ushort_t* dst    = blockIdx.y ? sb : db;
    const size_t i = ((size_t)blockIdx.x * 256 + threadIdx.x) * 4;
    float4 v = *(const float4*)(src + i);
    uint2 pv;
    pv.x = (uint_t)f2bf(v.x) | ((uint_t)f2bf(v.y) << 16);
    pv.y = (uint_t)f2bf(v.z) | ((uint_t)f2bf(v.w) << 16);
    *(uint2*)(dst + i) = pv;
}

// ---------------------------------------------------------------------------
// fp32 W[K][N] -> bf16 WT[N][K] for all 6 weights (grid.y selects weight)
// ---------------------------------------------------------------------------
__global__ __launch_bounds__(256) void transpose_w(
    const float* q, const float* k, const float* v, const float* o,
    const float* m0, const float* m1,
    ushort_t* qt, ushort_t* kt, ushort_t* vt, ushort_t* ot,
    ushort_t* m0t, ushort_t* m1t)
{
    const float* src; ushort_t* dst; int K, N;
    switch (blockIdx.y) {
        case 0: src = q;  dst = qt;  K = 256; N = 256; break;
        case 1: src = k;  dst = kt;  K = 256; N = 256; break;
        case 2: src = v;  dst = vt;  K = 256; N = 256; break;
        case 3: src = o;  dst = ot;  K = 256; N = 256; break;
        case 4: src = m0; dst = m0t; K = 512; N = 512; break;
        default: src = m1; dst = m1t; K = 512; N = 256; break;
    }
    const int idx = blockIdx.x * 256 + threadIdx.x;
    const int ksh = (K == 512) ? 6 : 5;          // K/8 as shift
    if (idx >= N << ksh >> 3 << 3 >> 3 << 3 ? idx >= (N * (K >> 3)) : idx >= (N * (K >> 3))) return;
    const int n  = idx >> ksh;
    const int kc = (idx & ((1 << ksh) - 1)) << 3;
    u16x8 pk;
#pragma unroll
    for (int j = 0; j < 8; j++) pk[j] = f2bf(src[(size_t)(kc + j) * N + n]);
    *(u16x8*)(dst + (size_t)n * K + kc) = pk;
}

// ---------------------------------------------------------------------------
// bf16 MFMA GEMM. Block tile: 64 tokens (M) x 128 channels (N), BK=64,
// 256 threads = 4 waves, wave tile 32x64 (2 mt x 4 nt of 16x16x32 MFMA).
// Act split column-wise: cols [0,K0) from A0, [K0,K) from A1 (BK=64 never
// straddles). WT is pre-transposed bf16 [N][K].
// MODE 0: swapped ops, bf16 head-major [b][h][s][64]          (q/k proj)
// MODE 1: swapped ops, bf16 row-major [tok][N]                (o-proj)
// MODE 2: swapped ops, bf16 row-major + BN + ReLU             (MLP0)
// MODE 3: swapped ops, fp32 row-major                         (MLP1 -> out)
// MODE 4: natural ops, bf16 head-transposed [b][h][dv][s]     (v proj)
// Swapped (A=WT, B=Act): D[n-local = (l>>4)*4+reg][tok-local = l&15]
//   -> 4 consecutive output channels per lane -> packed stores.
// Natural (A=Act, B=WT-as-B): D[tok-local][dv-local = l&15]
//   -> 4 consecutive tokens per lane -> packed stores into [dv][s].
// ---------------------------------------------------------------------------
template <int MODE>
__global__ __launch_bounds__(256) void gemm_mfma(
    const ushort_t* __restrict__ A0, const ushort_t* __restrict__ A1, int K0,
    const ushort_t* __restrict__ WT, const float* __restrict__ bias,
    const float* __restrict__ bng, const float* __restrict__ bnb,
    const float* __restrict__ bnm, const float* __restrict__ bnv,
    void* __restrict__ outp, int N, int K)
{
    __shared__ ushort_t Al[64 * PITCH];    // Act tile [m][k]
    __shared__ ushort_t Wl[128 * PITCH];   // WT tile  [n][k]

    const int t  = threadIdx.x;
    const int w  = t >> 6;
    const int l  = t & 63;
    const int lq = l & 15;
    const int lg = l >> 4;
    const int n0   = blockIdx.x << 7;
    const int row0 = blockIdx.y << 6;
    const int wm = (w & 1) * 32;    // wave token offset
    const int wn = (w >> 1) * 64;   // wave channel offset

    f32x4 acc[2][4];
#pragma unroll
    for (int mt = 0; mt < 2; mt++)
#pragma unroll
        for (int nt = 0; nt < 4; nt++) acc[mt][nt] = (f32x4){0.f, 0.f, 0.f, 0.f};

    for (int kt = 0; kt < K; kt += 64) {
        const bool first = (kt < K0);
        const ushort_t* Asrc = first ? A0 : A1;
        const int lda = first ? K0 : (K - K0);
        const int kb  = first ? kt : (kt - K0);
        __syncthreads();
        // stage Act: 64 rows x 64 k = 512 chunks of 16B, 2/thread
#pragma unroll
        for (int i = 0; i < 2; i++) {
            const int c = t + i * 256;
            const int r = c >> 3;
            const int k8 = (c & 7) << 3;
            *(bf16x8*)&Al[r * PITCH + k8] =
                *(const bf16x8*)(Asrc + (size_t)(row0 + r) * lda + kb + k8);
        }
        // stage WT: 128 rows x 64 k = 1024 chunks, 4/thread
#pragma unroll
        for (int i = 0; i < 4; i++) {
            const int c = t + i * 256;
            const int r = c >> 3;
            const int k8 = (c & 7) << 3;
            *(bf16x8*)&Wl[r * PITCH + k8] =
                *(const bf16x8*)(WT + (size_t)(n0 + r) * K + kt + k8);
        }
        __syncthreads();
#pragma unroll
        for (int kc = 0; kc < 2; kc++) {
            bf16x8 wf[4], af[2];
#pragma unroll
            for (int nt = 0; nt < 4; nt++)
                wf[nt] = *(const bf16x8*)&Wl[(wn + nt * 16 + lq) * PITCH + kc * 32 + lg * 8];
#pragma unroll
            for (int mt = 0; mt < 2; mt++)
                af[mt] = *(const bf16x8*)&Al[(wm + mt * 16 + lq) * PITCH + kc * 32 + lg * 8];
#pragma unroll
            for (int mt = 0; mt < 2; mt++)
#pragma unroll
                for (int nt = 0; nt < 4; nt++) {
                    if (MODE == 4)
                        acc[mt][nt] = MFMA16(af[mt], wf[nt], acc[mt][nt]);
                    else
                        acc[mt][nt] = MFMA16(wf[nt], af[mt], acc[mt][nt]);
                }
        }
    }

    if (MODE == 4) {
        // natural: lane holds 4 consecutive tokens at channel dv = lq
        ushort_t* vout = (ushort_t*)outp;
#pragma unroll
        for (int nt = 0; nt < 4; nt++) {
            const int dvg = n0 + wn + nt * 16 + lq;
            const int h  = dvg >> 6;
            const int dv = dvg & 63;
            const float bs = bias[dvg];
#pragma unroll
            for (int mt = 0; mt < 2; mt++) {
                const int tok0 = row0 + wm + mt * 16 + lg * 4;
                const int b = tok0 >> 11;
                const int s = tok0 & 2047;
                uint2 pv;
                ushort_t p0 = f2bf(acc[mt][nt][0] + bs);
                ushort_t p1 = f2bf(acc[mt][nt][1] + bs);
                ushort_t p2 = f2bf(acc[mt][nt][2] + bs);
                ushort_t p3 = f2bf(acc[mt][nt][3] + bs);
                pv.x = (uint_t)p0 | ((uint_t)p1 << 16);
                pv.y = (uint_t)p2 | ((uint_t)p3 << 16);
                *(uint2*)(vout + ((size_t)(b * NH + h) * NHD + dv) * NS + s) = pv;
            }
        }
    } else {
        // swapped: lane holds 4 consecutive channels at token = lq
#pragma unroll
        for (int nt = 0; nt < 4; nt++) {
            const int nb = n0 + wn + nt * 16 + lg * 4;
            f32x4 bs = *(const f32x4*)(bias + nb);
            f32x4 g4, b4, m4, v4;
            if (MODE == 2) {
                g4 = *(const f32x4*)(bng + nb);
                b4 = *(const f32x4*)(bnb + nb);
                m4 = *(const f32x4*)(bnm + nb);
                v4 = *(const f32x4*)(bnv + nb);
            }
#pragma unroll
            for (int mt = 0; mt < 2; mt++) {
                const int tok = row0 + wm + mt * 16 + lq;
                float r[4];
#pragma unroll
                for (int j = 0; j < 4; j++) {
                    float x = acc[mt][nt][j] + bs[j];
                    if (MODE == 2) {
                        x = (x - m4[j]) * rsqrtf(v4[j] + 1e-5f) * g4[j] + b4[j];
                        x = fmaxf(x, 0.0f);
                    }
                    r[j] = x;
                }
                if (MODE == 3) {
                    f32x4 o4 = {r[0], r[1], r[2], r[3]};
                    *(f32x4*)((float*)outp + (size_t)tok * N + nb) = o4;
                } else if (MODE == 0) {
                    const int b = tok >> 11;
                    const int s = tok & 2047;
                    const int h = nb >> 6;
                    const int d = nb & 63;
                    uint2 pv;
                    pv.x = (uint_t)f2bf(r[0]) | ((uint_t)f2bf(r[1]) << 16);
                    pv.y = (uint_t)f2bf(r[2]) | ((uint_t)f2bf(r[3]) << 16);
                    *(uint2*)((ushort_t*)outp + ((size_t)(b * NH + h) * NS + s) * NHD + d) = pv;
                } else {
                    uint2 pv;
                    pv.x = (uint_t)f2bf(r[0]) | ((uint_t)f2bf(r[1]) << 16);
                    pv.y = (uint_t)f2bf(r[2]) | ((uint_t)f2bf(r[3]) << 16);
                    *(uint2*)((ushort_t*)outp + (size_t)tok * N + nb) = pv;
                }
            }
        }
    }
}

// ---------------------------------------------------------------------------
// MFMA flash cross-attention (bf16 in, bf16 out). Same as round 3 except the
// epilogue writes bf16 ctx (feeds the bf16 o-proj GEMM).
// ---------------------------------------------------------------------------
__global__ __launch_bounds__(256) void attn_mfma(
    const ushort_t* __restrict__ qbf, const ushort_t* __restrict__ kbf,
    const ushort_t* __restrict__ vtbf, const int* __restrict__ mask,
    ushort_t* __restrict__ ctxb)
{
    __shared__ ushort_t Kl[64 * PITCH];
    __shared__ ushort_t Vl[64 * PITCH];
    __shared__ ushort_t Pl[4][16 * PITCH];

    const int t  = threadIdx.x;
    const int w  = t >> 6;
    const int l  = t & 63;
    const int lq = l & 15;
    const int lg = l >> 4;
    const int qb = blockIdx.x;
    const int h  = blockIdx.y;
    const int b  = blockIdx.z;
    const int bh = b * NH + h;

    const ushort_t* qh = qbf + (size_t)bh * NS * NHD;
    const ushort_t* kh = kbf + (size_t)bh * NS * NHD;
    const ushort_t* vh = vtbf + (size_t)bh * NHD * NS;
    const int* mrow = mask + b * NS;
    const int qrow0 = qb * 128 + w * 32;

    bf16x8 qf[2][2];
#pragma unroll
    for (int qt = 0; qt < 2; qt++)
#pragma unroll
        for (int dh = 0; dh < 2; dh++)
            qf[qt][dh] = *(const bf16x8*)(qh + (size_t)(qrow0 + qt * 16 + lq) * NHD
                                          + dh * 32 + lg * 8);

    f32x4 o[2][4];
#pragma unroll
    for (int qt = 0; qt < 2; qt++)
#pragma unroll
        for (int dt = 0; dt < 4; dt++) o[qt][dt] = (f32x4){0.f, 0.f, 0.f, 0.f};
    float m_run[2] = {-1e30f, -1e30f};
    float l_run[2] = {0.0f, 0.0f};

    for (int key0 = 0; key0 < NS; key0 += 64) {
        __syncthreads();
#pragma unroll
        for (int i = 0; i < 2; i++) {
            const int r  = (t >> 3) + i * 32;
            const int c8 = (t & 7) * 8;
            *(bf16x8*)&Kl[r * PITCH + c8] =
                *(const bf16x8*)(kh + (size_t)(key0 + r) * NHD + c8);
            *(bf16x8*)&Vl[r * PITCH + c8] =
                *(const bf16x8*)(vh + (size_t)r * NS + key0 + c8);
        }
        __syncthreads();

        int4 mv[4];
#pragma unroll
        for (int kt = 0; kt < 4; kt++)
            mv[kt] = *(const int4*)(mrow + key0 + kt * 16 + lg * 4);

#pragma unroll
        for (int qt = 0; qt < 2; qt++) {
            f32x4 st[4];
#pragma unroll
            for (int kt = 0; kt < 4; kt++) {
                bf16x8 ka0 = *(const bf16x8*)&Kl[(kt * 16 + lq) * PITCH + lg * 8];
                bf16x8 ka1 = *(const bf16x8*)&Kl[(kt * 16 + lq) * PITCH + 32 + lg * 8];
                f32x4 a = (f32x4){0.f, 0.f, 0.f, 0.f};
                a = MFMA16(ka0, qf[qt][0], a);
                a = MFMA16(ka1, qf[qt][1], a);
                st[kt] = a;
            }
            float cm = -1e30f;
#pragma unroll
            for (int kt = 0; kt < 4; kt++)
#pragma unroll
                for (int r = 0; r < 4; r++) {
                    float v = st[kt][r] * 0.125f;
                    const int mk = (&mv[kt].x)[r];
                    v = (mk == 0) ? -1e9f : v;
                    st[kt][r] = v;
                    cm = fmaxf(cm, v);
                }
            cm = fmaxf(cm, __shfl_xor(cm, 16));
            cm = fmaxf(cm, __shfl_xor(cm, 32));
            const float mn = fmaxf(m_run[qt], cm);
            const float al = __expf(m_run[qt] - mn);
            m_run[qt] = mn;
            float ls = 0.0f;
#pragma unroll
            for (int kt = 0; kt < 4; kt++) {
                ushort_t pb[4];
#pragma unroll
                for (int r = 0; r < 4; r++) {
                    const float p = __expf(st[kt][r] - mn);
                    ls += p;
                    pb[r] = f2bf(p);
                }
                uint2 pv;
                pv.x = (uint_t)pb[0] | ((uint_t)pb[1] << 16);
                pv.y = (uint_t)pb[2] | ((uint_t)pb[3] << 16);
                *(uint2*)&Pl[w][lq * PITCH + kt * 16 + lg * 4] = pv;
            }
            ls += __shfl_xor(ls, 16);
            ls += __shfl_xor(ls, 32);
            l_run[qt] = l_run[qt] * al + ls;
#pragma unroll
            for (int dt = 0; dt < 4; dt++)
#pragma unroll
                for (int r = 0; r < 4; r++) o[qt][dt][r] *= al;

            bf16x8 pf[2];
#pragma unroll
            for (int kh2 = 0; kh2 < 2; kh2++)
                pf[kh2] = *(const bf16x8*)&Pl[w][lq * PITCH + kh2 * 32 + lg * 8];
#pragma unroll
            for (int dt = 0; dt < 4; dt++)
#pragma unroll
                for (int kh2 = 0; kh2 < 2; kh2++) {
                    bf16x8 vf = *(const bf16x8*)&Vl[(dt * 16 + lq) * PITCH
                                                    + kh2 * 32 + lg * 8];
                    o[qt][dt] = MFMA16(vf, pf[kh2], o[qt][dt]);
                }
        }
    }

    // epilogue: divide by l, write bf16 ctx[token][256]
#pragma unroll
    for (int qt = 0; qt < 2; qt++) {
        const float li = 1.0f / l_run[qt];
        const int tok = b * NS + qrow0 + qt * 16 + lq;
#pragma unroll
        for (int dt = 0; dt < 4; dt++) {
            uint2 pv;
            pv.x = (uint_t)f2bf(o[qt][dt][0] * li) | ((uint_t)f2bf(o[qt][dt][1] * li) << 16);
            pv.y = (uint_t)f2bf(o[qt][dt][2] * li) | ((uint_t)f2bf(o[qt][dt][3] * li) << 16);
            *(uint2*)(ctxb + (size_t)tok * ND + h * NHD + dt * 16 + lg * 4) = pv;
        }
    }
}

extern "C" void kernel_launch(void* const* d_in, const int* in_sizes, int n_in,
                              void* d_out, int out_size, void* d_ws, size_t ws_size,
                              hipStream_t stream)
{
    (void)in_sizes; (void)n_in; (void)out_size; (void)ws_size;
    const float* desc = (const float*)d_in[0];
    const float* srcp = (const float*)d_in[1];
    const int*   mask = (const int*)d_in[2];
    const float* q_w  = (const float*)d_in[3];
    const float* q_b  = (const float*)d_in[4];
    const float* k_w  = (const float*)d_in[5];
    const float* k_b  = (const float*)d_in[6];
    const float* v_w  = (const float*)d_in[7];
    const float* v_b  = (const float*)d_in[8];
    const float* o_w  = (const float*)d_in[9];
    const float* o_b  = (const float*)d_in[10];
    const float* m0_w = (const float*)d_in[11];
    const float* m0_b = (const float*)d_in[12];
    const float* bng  = (const float*)d_in[13];
    const float* bnb  = (const float*)d_in[14];
    const float* bnm  = (const float*)d_in[15];
    const float* bnv  = (const float*)d_in[16];
    const float* m1_w = (const float*)d_in[17];
    const float* m1_b = (const float*)d_in[18];
    float* out = (float*)d_out;

    // workspace (all bf16 activations), ~43 MB total:
    //   [0]  desc_bf [NM][256]          (live until MLP0)
    //   [1]  src_bf  [NM][256]          -> reused as ctx_bf after V-proj
    //   [2]  qbf [b][h][s][64]          -> reused as abuf after attention
    //   [3]  kbf [b][h][s][64]          -> with [4] reused as hbuf after attn
    //   [4]  vtbf [b][h][dv][s]
    //   [5]  WT area: qwT,kwT,vwT,owT (64K each), m0T (256K), m1T (128K)
    const size_t ASZ = (size_t)NM * ND;  // 4,194,304 elems
    ushort_t* desc_bf = (ushort_t*)d_ws;
    ushort_t* src_bf  = desc_bf + ASZ;
    ushort_t* qbf     = desc_bf + 2 * ASZ;
    ushort_t* kbf     = desc_bf + 3 * ASZ;
    ushort_t* vtbf    = desc_bf + 4 * ASZ;
    ushort_t* qwT     = desc_bf + 5 * ASZ;
    ushort_t* kwT     = qwT + 65536;
    ushort_t* vwT     = kwT + 65536;
    ushort_t* owT     = vwT + 65536;
    ushort_t* m0T     = owT + 65536;
    ushort_t* m1T     = m0T + 262144;
    ushort_t* ctx_bf  = src_bf;   // src dead after V-proj
    ushort_t* abuf    = qbf;      // q dead after attention
    ushort_t* hbuf    = kbf;      // k+v dead after attention (16.8 MB span)

    const dim3 blk(256);

    convert_acts<<<dim3(ASZ / 1024, 2), blk, 0, stream>>>(desc, srcp, desc_bf, src_bf);
    transpose_w<<<dim3(128, 6), blk, 0, stream>>>(q_w, k_w, v_w, o_w, m0_w, m1_w,
                                                  qwT, kwT, vwT, owT, m0T, m1T);
    // QKV projections (MFMA)
    gemm_mfma<0><<<dim3(2, 256), blk, 0, stream>>>(desc_bf, desc_bf, ND, qwT, q_b,
                                                   bng, bnb, bnm, bnv, qbf, ND, ND);
    gemm_mfma<0><<<dim3(2, 256), blk, 0, stream>>>(src_bf, src_bf, ND, kwT, k_b,
                                                   bng, bnb, bnm, bnv, kbf, ND, ND);
    gemm_mfma<4><<<dim3(2, 256), blk, 0, stream>>>(src_bf, src_bf, ND, vwT, v_b,
                                                   bng, bnb, bnm, bnv, vtbf, ND, ND);
    // flash attention -> bf16 ctx
    attn_mfma<<<dim3(NS / 128, NH, NB), blk, 0, stream>>>(qbf, kbf, vtbf, mask, ctx_bf);
    // out_proj
    gemm_mfma<1><<<dim3(2, 256), blk, 0, stream>>>(ctx_bf, ctx_bf, ND, owT, o_b,
                                                   bng, bnb, bnm, bnv, abuf, ND, ND);
    // MLP0: concat(desc, attn) -> BN -> ReLU
    gemm_mfma<2><<<dim3(4, 256), blk, 0, stream>>>(desc_bf, abuf, ND, m0T, m0_b,
                                                   bng, bnb, bnm, bnv, hbuf, ND2, ND2);
    // MLP1 -> fp32 out
    gemm_mfma<3><<<dim3(2, 256), blk, 0, stream>>>(hbuf, hbuf, ND2, m1T, m1_b,
                                                   bng, bnb, bnm, bnv, out, ND, ND2);
}